// Round 9
// baseline (432.755 us; speedup 1.0000x reference)
//
#include <hip/hip_runtime.h>
#include <hip/hip_bf16.h>

// SNN forward: out = mean_t s3(t). B=16384, n_in=512, n_hid=1024, n_out=6, T=16.
// ws layout (50 MB): [0,32M) i1h f16; [32M,48M) xh f16; [48M,49M) W1h f16;
//   [49M,50M) W2u u8 [k][j] (W2^T, q = rint(w*4064) clamp +-127, stored q+128)

typedef _Float16 f16;
typedef __attribute__((ext_vector_type(4))) _Float16 f16x4;
typedef __attribute__((ext_vector_type(8))) _Float16 f16x8;
typedef __attribute__((ext_vector_type(4))) float f32x4;

// ---------------- K0: convert x and W1 to f16 ----------------
__global__ __launch_bounds__(256) void k_cvt(const float* __restrict__ x,
                                             const float* __restrict__ W1,
                                             f16* __restrict__ xh,
                                             f16* __restrict__ W1h) {
    const int NX = 16384 * 512 / 4;
    const int NW = 1024 * 512 / 4;
    int i = blockIdx.x * 256 + threadIdx.x;
    const int stride = gridDim.x * 256;
    for (; i < NX + NW; i += stride) {
        const float4* src;
        f16* dst;
        int j;
        if (i < NX) { src = (const float4*)x; dst = xh; j = i; }
        else        { src = (const float4*)W1; dst = W1h; j = i - NX; }
        float4 v = src[j];
        f16x4 h;
        h.x = (f16)v.x; h.y = (f16)v.y; h.z = (f16)v.z; h.w = (f16)v.w;
        *(f16x4*)(dst + (size_t)4 * j) = h;
    }
}

// ---------------- K1: W2 -> W2u = u8(int8(W2^T * 4064) + 128) ----------------
__global__ void k_tq(const float* __restrict__ W2, unsigned char* __restrict__ W2u) {
    __shared__ float t[32][33];
    const int bj = blockIdx.x;
    const int bk = blockIdx.y;
    const int tx = threadIdx.x;
    const int ty = threadIdx.y;
#pragma unroll
    for (int i = 0; i < 32; i += 8)
        t[ty + i][tx] = W2[(size_t)(bj * 32 + ty + i) * 1024 + bk * 32 + tx];
    __syncthreads();
#pragma unroll
    for (int i = 0; i < 32; i += 8) {
        float v = t[tx][ty + i];
        int q = (int)rintf(v * 4064.0f);
        q = q > 127 ? 127 : (q < -127 ? -127 : q);
        W2u[(size_t)(bk * 32 + ty + i) * 1024 + bj * 32 + tx] = (unsigned char)(q + 128);
    }
}

// ---------------- K2: i1 = xh @ W1h^T + b1 (f16 MFMA GEMM, f16 out) --------
__global__ __launch_bounds__(256) void k_fc1(const f16* __restrict__ xh,
                                             const f16* __restrict__ W1h,
                                             const float* __restrict__ b1,
                                             f16* __restrict__ i1h) {
    __shared__ __align__(16) f16 Atile[128 * 32];
    __shared__ __align__(16) f16 Btile[256 * 32];
    const int tid = threadIdx.x;
    const int lane = tid & 63;
    const int wid = tid >> 6;
    const int wm = wid >> 1;
    const int wn = wid & 1;
    const int m0 = blockIdx.x * 128;
    const int n0 = blockIdx.y * 256;

    f32x4 acc[4][8] = {};

    for (int k0 = 0; k0 < 512; k0 += 32) {
        __syncthreads();
#pragma unroll
        for (int q = 0; q < 6; ++q) {
            const bool isA = (q < 2);
            int u = q * 256 + tid;
            int cu = isA ? u : (u - 512);
            int rl = cu >> 2;
            int slot = (cu & 3) ^ (rl & 3);
            const f16* g = isA
                ? xh  + (size_t)(m0 + rl) * 512 + k0 + slot * 8
                : W1h + (size_t)(n0 + rl) * 512 + k0 + slot * 8;
            f16x8 v = *(const f16x8*)g;
            f16* d = (isA ? Atile : Btile) + (size_t)cu * 8;
            *(f16x8*)d = v;
        }
        __syncthreads();
        f16x8 af[4], bf[8];
#pragma unroll
        for (int i = 0; i < 4; ++i) {
            int rowA = (wm << 6) + (i << 4) + (lane & 15);
            af[i] = *(const f16x8*)(Atile + rowA * 32 + (((lane >> 4) ^ (rowA & 3)) << 3));
        }
#pragma unroll
        for (int j = 0; j < 8; ++j) {
            int rowB = (wn << 7) + (j << 4) + (lane & 15);
            bf[j] = *(const f16x8*)(Btile + rowB * 32 + (((lane >> 4) ^ (rowB & 3)) << 3));
        }
#pragma unroll
        for (int i = 0; i < 4; ++i)
#pragma unroll
            for (int j = 0; j < 8; ++j)
                acc[i][j] = __builtin_amdgcn_mfma_f32_16x16x32_f16(af[i], bf[j], acc[i][j], 0, 0, 0);
    }

    float b1v[8];
#pragma unroll
    for (int j = 0; j < 8; ++j)
        b1v[j] = b1[n0 + (wn << 7) + (j << 4) + (lane & 15)];
#pragma unroll
    for (int i = 0; i < 4; ++i) {
        int rm = m0 + (wm << 6) + (i << 4) + ((lane >> 4) << 2);
#pragma unroll
        for (int j = 0; j < 8; ++j) {
            int cn = n0 + (wn << 7) + (j << 4) + (lane & 15);
            f16* op = i1h + (size_t)rm * 1024 + cn;
#pragma unroll
            for (int rr = 0; rr < 4; ++rr)
                op[(size_t)rr * 1024] = (f16)(acc[i][j][rr] + b1v[j]);
        }
    }
}

// ---------------- K3: fused T-loop LIF, list-then-gather ----------------
// Phase A: 16-bit spike train per neuron (no layer-1 feedback => pure fn of i1).
// Phase B (per 8-t half): (1) compact firing (k | train<<16) into an LDS list
// via ballot + prefix-popcount (no loads in the discovery path); (2) uniform
// 4-wide software-pipelined gather over the list (next batch's 4 row-loads in
// flight while current 4 rows scatter-add into per-t SWAR u16 accumulators
// under wave-uniform scalar branches). Exact integer accumulation; bias 128*n
// removed per t via wave-reduced counts. fc3 fast path: 1 ballot/t when no s2.
// Mappings: layer-1 k = 4*lane + 256*g + e; layer-2 j = 16*lane + 4*d + c.
__global__ __launch_bounds__(256) void k_snn(const f16* __restrict__ i1g,
                                             const unsigned char* __restrict__ W2u,
                                             const float* __restrict__ b2,
                                             const float* __restrict__ W3,
                                             const float* __restrict__ b3,
                                             float* __restrict__ out) {
    __shared__ unsigned lst[4][272];  // per-wave firing list (max 256 + 8 pad)
    const int lane = threadIdx.x & 63;
    const int wid = threadIdx.x >> 6;
    const int r = blockIdx.x * 4 + wid;
    const float DEQ = 1.0f / 4064.0f;

    // ---- Phase A ----
    unsigned train[16];
    unsigned cnt[8] = {};  // u16 SWAR per-t fire counts {t even | t odd}
    const f16x4* i1p4 = (const f16x4*)(i1g + (size_t)r * 1024);
#pragma unroll
    for (int g = 0; g < 4; ++g) {
        f16x4 tq = i1p4[lane + 64 * g];
#pragma unroll
        for (int e = 0; e < 4; ++e) {
            float iv = (float)tq[e];
            float v = 0.0f;
            unsigned tr = 0u;
#pragma unroll
            for (int t = 0; t < 16; ++t) {
                v = v + (iv - v) * 0.5f;          // == v + (i-v)/TAU exactly
                unsigned su = (v >= 1.0f) ? 1u : 0u;
                v = su ? 0.0f : v;
                tr |= su << t;
                cnt[t >> 1] += su << ((t & 1) * 16);
            }
            train[4 * g + e] = tr;
        }
    }
#pragma unroll
    for (int st = 1; st < 64; st <<= 1)
#pragma unroll
        for (int h = 0; h < 8; ++h)
            cnt[h] += __shfl_xor(cnt[h], st, 64);

    float b2r[16];
#pragma unroll
    for (int q = 0; q < 4; ++q) {
        float4 u = ((const float4*)b2)[lane * 4 + q];
        b2r[4 * q + 0] = u.x; b2r[4 * q + 1] = u.y;
        b2r[4 * q + 2] = u.z; b2r[4 * q + 3] = u.w;
    }
    float b3r[6];
#pragma unroll
    for (int m6 = 0; m6 < 6; ++m6) b3r[m6] = b3[m6];

    const uint4* w2v = (const uint4*)W2u;  // row k = w2v[k*64 + lane]

    float v2[16] = {}, v3[6] = {}, cnt3[6] = {};

#pragma unroll
    for (int half = 0; half < 2; ++half) {
        // ---- build firing list for t in [8*half, 8*half+8) ----
        int n = 0;
#pragma unroll
        for (int g = 0; g < 4; ++g)
#pragma unroll
            for (int e = 0; e < 4; ++e) {
                unsigned sub = (train[4 * g + e] >> (half * 8)) & 0xFFu;
                unsigned long long m = __ballot(sub != 0u);
                if (m) {
                    int idx = (int)__popcll(m & ((1ull << lane) - 1ull));
                    if (sub)
                        lst[wid][n + idx] =
                            (unsigned)(4 * lane + 256 * g + e) | (sub << 16);
                    n += (int)__popcll(m);
                }
            }
        if (lane < 8) lst[wid][n + lane] = 0u;  // pad: k=0, train=0

        unsigned accE[8][4] = {};  // u16 SWAR: elems 4d+0 (lo), 4d+2 (hi)
        unsigned accO[8][4] = {};  // u16 SWAR: elems 4d+1 (lo), 4d+3 (hi)

        if (n) {
            // ---- 4-wide software-pipelined gather ----
            unsigned enA[4];
            uint4 wA[4];
#pragma unroll
            for (int u = 0; u < 4; ++u) {
                enA[u] = lst[wid][u];
                wA[u] = w2v[(size_t)(enA[u] & 0xFFFFu) * 64 + lane];
            }
            for (int i = 0; i < n; i += 4) {
                unsigned enB[4];
                uint4 wB[4];
#pragma unroll
                for (int u = 0; u < 4; ++u) {
                    enB[u] = lst[wid][i + 4 + u];  // <= n+7, in bounds
                    wB[u] = w2v[(size_t)(enB[u] & 0xFFFFu) * 64 + lane];
                }
#pragma unroll
                for (int u = 0; u < 4; ++u) {
                    unsigned tr = __builtin_amdgcn_readfirstlane(enA[u]) >> 16;
                    unsigned E[4], O[4];
                    E[0] = __builtin_amdgcn_perm(0u, wA[u].x, 0x04020400u);
                    O[0] = __builtin_amdgcn_perm(0u, wA[u].x, 0x04030401u);
                    E[1] = __builtin_amdgcn_perm(0u, wA[u].y, 0x04020400u);
                    O[1] = __builtin_amdgcn_perm(0u, wA[u].y, 0x04030401u);
                    E[2] = __builtin_amdgcn_perm(0u, wA[u].z, 0x04020400u);
                    O[2] = __builtin_amdgcn_perm(0u, wA[u].z, 0x04030401u);
                    E[3] = __builtin_amdgcn_perm(0u, wA[u].w, 0x04020400u);
                    O[3] = __builtin_amdgcn_perm(0u, wA[u].w, 0x04030401u);
#pragma unroll
                    for (int tt = 0; tt < 8; ++tt)
                        if (tr & (1u << tt)) {  // wave-uniform scalar branch
#pragma unroll
                            for (int d = 0; d < 4; ++d) {
                                accE[tt][d] += E[d];
                                accO[tt][d] += O[d];
                            }
                        }
                }
#pragma unroll
                for (int u = 0; u < 4; ++u) { enA[u] = enB[u]; wA[u] = wB[u]; }
            }
        }

        // ---- LIF2 + fc3 + LIF3, t sequential within half ----
#pragma unroll
        for (int tt = 0; tt < 8; ++tt) {
            const int t = half * 8 + tt;
            const int nr = (int)((cnt[t >> 1] >> ((t & 1) * 16)) & 0xFFFFu);
            const int bias = nr << 7;
            bool s2[16];
            bool any2 = false;
#pragma unroll
            for (int d = 0; d < 4; ++d) {
                int sq[4];
                sq[0] = (int)(accE[tt][d] & 0xFFFFu) - bias;
                sq[1] = (int)(accO[tt][d] & 0xFFFFu) - bias;
                sq[2] = (int)(accE[tt][d] >> 16) - bias;
                sq[3] = (int)(accO[tt][d] >> 16) - bias;
#pragma unroll
                for (int c = 0; c < 4; ++c) {
                    int e = 4 * d + c;
                    float i2 = fmaf((float)sq[c], DEQ, b2r[e]);
                    float v = v2[e];
                    v = v + (i2 - v) * 0.5f;
                    bool s = v >= 1.0f;
                    s2[e] = s;
                    any2 |= s;
                    v2[e] = s ? 0.0f : v;
                }
            }
            float i3[6];
#pragma unroll
            for (int m6 = 0; m6 < 6; ++m6) i3[m6] = b3r[m6];
            if (__ballot(any2 ? 1 : 0)) {  // statistically ~never taken
#pragma unroll
                for (int e = 0; e < 16; ++e) {
                    unsigned long long mm = __ballot(s2[e] ? 1 : 0);
                    while (mm) {
                        int b = __builtin_ctzll(mm);
                        mm &= mm - 1;
                        int j = 16 * b + e;
#pragma unroll
                        for (int m6 = 0; m6 < 6; ++m6) i3[m6] += W3[m6 * 1024 + j];
                    }
                }
            }
#pragma unroll
            for (int m6 = 0; m6 < 6; ++m6) {
                float v = v3[m6];
                v = v + (i3[m6] - v) * 0.5f;
                bool s = v >= 1.0f;
                cnt3[m6] += s ? 1.0f : 0.0f;
                v3[m6] = s ? 0.0f : v;
            }
        }
    }
    if (lane == 0) {
#pragma unroll
        for (int m6 = 0; m6 < 6; ++m6)
            out[(size_t)r * 6 + m6] = cnt3[m6] * 0.0625f;
    }
}

extern "C" void kernel_launch(void* const* d_in, const int* in_sizes, int n_in,
                              void* d_out, int out_size, void* d_ws, size_t ws_size,
                              hipStream_t stream) {
    const float* x  = (const float*)d_in[0];
    const float* W1 = (const float*)d_in[1];
    const float* b1 = (const float*)d_in[2];
    const float* W2 = (const float*)d_in[3];
    const float* b2 = (const float*)d_in[4];
    const float* W3 = (const float*)d_in[5];
    const float* b3 = (const float*)d_in[6];
    float* out = (float*)d_out;

    char* ws = (char*)d_ws;
    f16* i1h = (f16*)ws;                                      // 32 MB
    f16* xh  = (f16*)(ws + ((size_t)32 << 20));               // 16 MB
    f16* W1h = (f16*)(ws + ((size_t)48 << 20));               // 1 MB
    unsigned char* W2u = (unsigned char*)(ws + ((size_t)49 << 20));  // 1 MB

    k_cvt<<<2048, 256, 0, stream>>>(x, W1, xh, W1h);
    k_tq<<<dim3(32, 32), dim3(32, 8), 0, stream>>>(W2, W2u);
    k_fc1<<<dim3(128, 4), 256, 0, stream>>>(xh, W1h, b1, i1h);
    k_snn<<<4096, 256, 0, stream>>>(i1h, W2u, b2, W3, b3, out);
}

// Round 14
// 369.274 us; speedup vs baseline: 1.1719x; 1.1719x over previous
//
#include <hip/hip_runtime.h>
#include <hip/hip_bf16.h>

// SNN forward: out = mean_t s3(t). B=16384, n_in=512, n_hid=1024, n_out=6, T=16.
// ws layout (33 MB): [0,32M) i1h f16 [16384,1024];
//   [32M,33M) W2u u8 [k][j] (W2^T, q = rint(w*4064) clamp +-127, stored q+128)

typedef _Float16 f16;
typedef __attribute__((ext_vector_type(4))) _Float16 f16x4;
typedef __attribute__((ext_vector_type(8))) _Float16 f16x8;
typedef __attribute__((ext_vector_type(4))) float f32x4;

// ---------------- K1: W2 -> W2u = u8(int8(W2^T * 4064) + 128) ----------------
__global__ void k_tq(const float* __restrict__ W2, unsigned char* __restrict__ W2u) {
    __shared__ float t[32][33];
    const int bj = blockIdx.x;
    const int bk = blockIdx.y;
    const int tx = threadIdx.x;
    const int ty = threadIdx.y;
#pragma unroll
    for (int i = 0; i < 32; i += 8)
        t[ty + i][tx] = W2[(size_t)(bj * 32 + ty + i) * 1024 + bk * 32 + tx];
    __syncthreads();
#pragma unroll
    for (int i = 0; i < 32; i += 8) {
        float v = t[tx][ty + i];
        int q = (int)rintf(v * 4064.0f);
        q = q > 127 ? 127 : (q < -127 ? -127 : q);
        W2u[(size_t)(bk * 32 + ty + i) * 1024 + bj * 32 + tx] = (unsigned char)(q + 128);
    }
}

// ---------------- K2: i1 = x @ W1^T + b1 (fused fp32->f16 + MFMA GEMM) -----
// M=16384, N=1024, K=512. BM=128, BN=256, BK=32. 256 threads = 4 waves (2x2).
// Staging loads fp32 float4 (16B), converts to f16x4, ds_write_b64 (8B),
// with the 16B-slot XOR swizzle (slot ^ (row&3)) applied on the SOURCE col
// and on the compute-phase READ (rule #21 involution); LDS dest stays linear.
__global__ __launch_bounds__(256) void k_fc1(const float* __restrict__ x,
                                             const float* __restrict__ W1,
                                             const float* __restrict__ b1,
                                             f16* __restrict__ i1h) {
    __shared__ __align__(16) f16 Atile[128 * 32];  // 8KB
    __shared__ __align__(16) f16 Btile[256 * 32];  // 16KB
    const int tid = threadIdx.x;
    const int lane = tid & 63;
    const int wid = tid >> 6;
    const int wm = wid >> 1;
    const int wn = wid & 1;
    const int m0 = blockIdx.x * 128;
    const int n0 = blockIdx.y * 256;

    f32x4 acc[4][8] = {};

    for (int k0 = 0; k0 < 512; k0 += 32) {
        __syncthreads();
        // 24KB f16 tile = 3072 8B-units; thread handles units q*256+tid.
        // unit cu: row = cu>>3, dest 16B slot d = (cu>>1)&3, half h = cu&1.
#pragma unroll
        for (int q = 0; q < 12; ++q) {
            const bool isA = (q < 4);
            int u = q * 256 + tid;
            int cu = isA ? u : (u - 1024);
            int rl = cu >> 3;
            int d = (cu >> 1) & 3;
            int h = cu & 1;
            int scol = ((d ^ (rl & 3)) << 3) + (h << 2);  // swizzled source col
            const float* g = isA
                ? x  + (size_t)(m0 + rl) * 512 + k0 + scol
                : W1 + (size_t)(n0 + rl) * 512 + k0 + scol;
            float4 v = *(const float4*)g;
            f16x4 hv;
            hv.x = (f16)v.x; hv.y = (f16)v.y; hv.z = (f16)v.z; hv.w = (f16)v.w;
            f16* dst = (isA ? Atile : Btile) + (size_t)cu * 4;  // linear dest
            *(f16x4*)dst = hv;
        }
        __syncthreads();
        f16x8 af[4], bf[8];
#pragma unroll
        for (int i = 0; i < 4; ++i) {
            int rowA = (wm << 6) + (i << 4) + (lane & 15);
            af[i] = *(const f16x8*)(Atile + rowA * 32 + (((lane >> 4) ^ (rowA & 3)) << 3));
        }
#pragma unroll
        for (int j = 0; j < 8; ++j) {
            int rowB = (wn << 7) + (j << 4) + (lane & 15);
            bf[j] = *(const f16x8*)(Btile + rowB * 32 + (((lane >> 4) ^ (rowB & 3)) << 3));
        }
#pragma unroll
        for (int i = 0; i < 4; ++i)
#pragma unroll
            for (int j = 0; j < 8; ++j)
                acc[i][j] = __builtin_amdgcn_mfma_f32_16x16x32_f16(af[i], bf[j], acc[i][j], 0, 0, 0);
    }

    float b1v[8];
#pragma unroll
    for (int j = 0; j < 8; ++j)
        b1v[j] = b1[n0 + (wn << 7) + (j << 4) + (lane & 15)];
#pragma unroll
    for (int i = 0; i < 4; ++i) {
        int rm = m0 + (wm << 6) + (i << 4) + ((lane >> 4) << 2);
#pragma unroll
        for (int j = 0; j < 8; ++j) {
            int cn = n0 + (wn << 7) + (j << 4) + (lane & 15);
            f16* op = i1h + (size_t)rm * 1024 + cn;
#pragma unroll
            for (int rr = 0; rr < 4; ++rr)
                op[(size_t)rr * 1024] = (f16)(acc[i][j][rr] + b1v[j]);
        }
    }
}

// ---------------- K3: fused T-loop LIF with spike-train dedup ----------------
// R8 structure (measured best: 271 us) with 1-wave blocks for straggler-free
// retirement + finer residency. Phase A: 16-bit spike train per neuron (layer 1
// has no feedback). Phase B per 8-t half: ballot-driven gather of unique firing
// rows, 2-deep pipelined, SWAR u16 scatter-add under wave-uniform branches.
// Exact integer accumulation; bias 128*n removed per t via wave-reduced counts.
// Mappings: layer-1 k = 4*lane + 256*g + e; layer-2 j = 16*lane + 4*d + c.
__global__ __launch_bounds__(64, 4) void k_snn(const f16* __restrict__ i1g,
                                               const unsigned char* __restrict__ W2u,
                                               const float* __restrict__ b2,
                                               const float* __restrict__ W3,
                                               const float* __restrict__ b3,
                                               float* __restrict__ out) {
    const int lane = threadIdx.x & 63;
    const int r = blockIdx.x;
    const float DEQ = 1.0f / 4064.0f;

    // ---- Phase A: spike trains + per-t fire counts ----
    unsigned train[16];
    unsigned cnt[8] = {};  // u16 SWAR per-t fire counts {t even | t odd}
    const f16x4* i1p4 = (const f16x4*)(i1g + (size_t)r * 1024);
#pragma unroll
    for (int g = 0; g < 4; ++g) {
        f16x4 tq = i1p4[lane + 64 * g];
#pragma unroll
        for (int e = 0; e < 4; ++e) {
            float iv = (float)tq[e];
            float v = 0.0f;
            unsigned tr = 0u;
#pragma unroll
            for (int t = 0; t < 16; ++t) {
                v = v + (iv - v) * 0.5f;          // == v + (i-v)/TAU exactly
                unsigned su = (v >= 1.0f) ? 1u : 0u;
                v = su ? 0.0f : v;
                tr |= su << t;
                cnt[t >> 1] += su << ((t & 1) * 16);
            }
            train[4 * g + e] = tr;
        }
    }
#pragma unroll
    for (int st = 1; st < 64; st <<= 1)
#pragma unroll
        for (int h = 0; h < 8; ++h)
            cnt[h] += __shfl_xor(cnt[h], st, 64);

    float b2r[16];
#pragma unroll
    for (int q = 0; q < 4; ++q) {
        float4 u = ((const float4*)b2)[lane * 4 + q];
        b2r[4 * q + 0] = u.x; b2r[4 * q + 1] = u.y;
        b2r[4 * q + 2] = u.z; b2r[4 * q + 3] = u.w;
    }
    float b3r[6];
#pragma unroll
    for (int m6 = 0; m6 < 6; ++m6) b3r[m6] = b3[m6];

    const uint4* w2v = (const uint4*)W2u;  // row k = w2v[k*64 + lane]

    float v2[16] = {}, v3[6] = {}, cnt3[6] = {};

#pragma unroll
    for (int half = 0; half < 2; ++half) {
        unsigned accE[8][4] = {};  // u16 SWAR: elems 4d+0 (lo), 4d+2 (hi)
        unsigned accO[8][4] = {};  // u16 SWAR: elems 4d+1 (lo), 4d+3 (hi)
#pragma unroll
        for (int g = 0; g < 4; ++g)
#pragma unroll
            for (int e = 0; e < 4; ++e) {
                unsigned sub = (train[4 * g + e] >> (half * 8)) & 0xFFu;
                unsigned long long m = __ballot(sub != 0u);
                if (m) {
                    int b0 = __builtin_ctzll(m); m &= m - 1;
                    unsigned tr0 = __builtin_amdgcn_readlane(sub, b0);
                    uint4 w0 = w2v[(size_t)(4 * b0 + 256 * g + e) * 64 + lane];
                    while (m) {
                        int b1 = __builtin_ctzll(m); m &= m - 1;
                        unsigned tr1 = __builtin_amdgcn_readlane(sub, b1);
                        uint4 w1 = w2v[(size_t)(4 * b1 + 256 * g + e) * 64 + lane];
                        // process w0 while w1 is in flight
                        unsigned E[4], O[4];
                        E[0] = __builtin_amdgcn_perm(0u, w0.x, 0x04020400u);
                        O[0] = __builtin_amdgcn_perm(0u, w0.x, 0x04030401u);
                        E[1] = __builtin_amdgcn_perm(0u, w0.y, 0x04020400u);
                        O[1] = __builtin_amdgcn_perm(0u, w0.y, 0x04030401u);
                        E[2] = __builtin_amdgcn_perm(0u, w0.z, 0x04020400u);
                        O[2] = __builtin_amdgcn_perm(0u, w0.z, 0x04030401u);
                        E[3] = __builtin_amdgcn_perm(0u, w0.w, 0x04020400u);
                        O[3] = __builtin_amdgcn_perm(0u, w0.w, 0x04030401u);
#pragma unroll
                        for (int tt = 0; tt < 8; ++tt)
                            if (tr0 & (1u << tt)) {  // wave-uniform scalar branch
#pragma unroll
                                for (int d = 0; d < 4; ++d) {
                                    accE[tt][d] += E[d];
                                    accO[tt][d] += O[d];
                                }
                            }
                        tr0 = tr1; w0 = w1;
                    }
                    {   // last row
                        unsigned E[4], O[4];
                        E[0] = __builtin_amdgcn_perm(0u, w0.x, 0x04020400u);
                        O[0] = __builtin_amdgcn_perm(0u, w0.x, 0x04030401u);
                        E[1] = __builtin_amdgcn_perm(0u, w0.y, 0x04020400u);
                        O[1] = __builtin_amdgcn_perm(0u, w0.y, 0x04030401u);
                        E[2] = __builtin_amdgcn_perm(0u, w0.z, 0x04020400u);
                        O[2] = __builtin_amdgcn_perm(0u, w0.z, 0x04030401u);
                        E[3] = __builtin_amdgcn_perm(0u, w0.w, 0x04020400u);
                        O[3] = __builtin_amdgcn_perm(0u, w0.w, 0x04030401u);
#pragma unroll
                        for (int tt = 0; tt < 8; ++tt)
                            if (tr0 & (1u << tt)) {
#pragma unroll
                                for (int d = 0; d < 4; ++d) {
                                    accE[tt][d] += E[d];
                                    accO[tt][d] += O[d];
                                }
                            }
                    }
                }
            }
        // ---- LIF2 + fc3 + LIF3, t sequential within half ----
#pragma unroll
        for (int tt = 0; tt < 8; ++tt) {
            const int t = half * 8 + tt;
            const int nr = (int)((cnt[t >> 1] >> ((t & 1) * 16)) & 0xFFFFu);
            const int bias = nr << 7;
            bool s2[16];
            bool any2 = false;
#pragma unroll
            for (int d = 0; d < 4; ++d) {
                int sq[4];
                sq[0] = (int)(accE[tt][d] & 0xFFFFu) - bias;
                sq[1] = (int)(accO[tt][d] & 0xFFFFu) - bias;
                sq[2] = (int)(accE[tt][d] >> 16) - bias;
                sq[3] = (int)(accO[tt][d] >> 16) - bias;
#pragma unroll
                for (int c = 0; c < 4; ++c) {
                    int e = 4 * d + c;
                    float i2 = fmaf((float)sq[c], DEQ, b2r[e]);
                    float v = v2[e];
                    v = v + (i2 - v) * 0.5f;
                    bool s = v >= 1.0f;
                    s2[e] = s;
                    any2 |= s;
                    v2[e] = s ? 0.0f : v;
                }
            }
            float i3[6];
#pragma unroll
            for (int m6 = 0; m6 < 6; ++m6) i3[m6] = b3r[m6];
            if (__ballot(any2 ? 1 : 0)) {  // statistically ~never taken
#pragma unroll
                for (int e = 0; e < 16; ++e) {
                    unsigned long long mm = __ballot(s2[e] ? 1 : 0);
                    while (mm) {
                        int b = __builtin_ctzll(mm);
                        mm &= mm - 1;
                        int j = 16 * b + e;
#pragma unroll
                        for (int m6 = 0; m6 < 6; ++m6) i3[m6] += W3[m6 * 1024 + j];
                    }
                }
            }
#pragma unroll
            for (int m6 = 0; m6 < 6; ++m6) {
                float v = v3[m6];
                v = v + (i3[m6] - v) * 0.5f;
                bool s = v >= 1.0f;
                cnt3[m6] += s ? 1.0f : 0.0f;
                v3[m6] = s ? 0.0f : v;
            }
        }
    }
    if (lane == 0) {
#pragma unroll
        for (int m6 = 0; m6 < 6; ++m6)
            out[(size_t)r * 6 + m6] = cnt3[m6] * 0.0625f;
    }
}

extern "C" void kernel_launch(void* const* d_in, const int* in_sizes, int n_in,
                              void* d_out, int out_size, void* d_ws, size_t ws_size,
                              hipStream_t stream) {
    const float* x  = (const float*)d_in[0];
    const float* W1 = (const float*)d_in[1];
    const float* b1 = (const float*)d_in[2];
    const float* W2 = (const float*)d_in[3];
    const float* b2 = (const float*)d_in[4];
    const float* W3 = (const float*)d_in[5];
    const float* b3 = (const float*)d_in[6];
    float* out = (float*)d_out;

    char* ws = (char*)d_ws;
    f16* i1h = (f16*)ws;                                          // 32 MB
    unsigned char* W2u = (unsigned char*)(ws + ((size_t)32 << 20));  // 1 MB

    k_tq<<<dim3(32, 32), dim3(32, 8), 0, stream>>>(W2, W2u);
    k_fc1<<<dim3(128, 4), 256, 0, stream>>>(x, W1, b1, i1h);
    k_snn<<<16384, 64, 0, stream>>>(i1h, W2u, b2, W3, b3, out);
}